// Round 2
// baseline (263.879 us; speedup 1.0000x reference)
//
#include <hip/hip_runtime.h>
#include <math.h>

// (256, 4096, 33) f32 rows: [K, w1[0..31]]; K passes through; w1 gets
// 4x (31-step push-apart scan + clip). One thread per row, row in registers.
//
// R3 post-mortem: R1 (256-thr bulk-sync), R2 (128-thr bulk-sync), R3
// (1-wave counted-vmcnt pipeline) ALL land at 83-84 us / 2.5 TB/s. The
// only shared element: all input bytes ingested via global_load_lds.
// Theory: the LDS-DMA path has a small per-CU outstanding-line budget;
// at HBM-miss latency (~900 cyc) that caps ingest at ~4.5 B/cyc/CU
// (= 2.7 TB/s chip) regardless of wave count -- exactly what we measure.
// (Same budget at L2 latency ~200 cyc gives ~20 B/cyc/CU = m97's GEMM
// staging rate, so the theory is consistent with the DMA being fast there.)
// Write-only fills (6.6 TB/s) and reg-load copy ubench (6.3 TB/s) prove
// the HBM path itself is fine.
// R4: NO global_load_lds. Reg-staged pipeline per 64-row tile:
//   global_load_dwordx4 x9 -> regs -> ds_write_b128 (stage) ->
//   issue NEXT tile's loads (stay in flight under compute; compiler
//   emits counted vmcnt before next iter's staging writes) ->
//   ds_read rows -> compute in regs -> ds_write rows ->
//   ds_read_b128 + global_store_dwordx4 (coalesced).
// Single-wave blocks (no barriers, per-wave in-order DS pipe makes the
// single LDS buffer WAR-safe); single 8.4 KB buffer -> 16 blocks/CU.

#define THREADS 64
#define ROW 33
#define TROWS 64                  // rows per tile (= one wave)
#define FPT (TROWS * ROW)         // 2112 floats per tile (8448 B)
#define V4PT (FPT / 4)            // 528 float4 per tile
#define TAIL (V4PT - 8 * THREADS) // 16-lane ragged tail
#define GRID 4096                 // 16 blocks/CU, 4 tiles per block

__global__ __launch_bounds__(THREADS) void lsp_stability_kernel(
    const float* __restrict__ in, float* __restrict__ out, int tiles)
{
    __shared__ alignas(16) float smem[FPT];
    const int tid = threadIdx.x;
    const int bid = blockIdx.x;
    if (bid >= tiles) return;
    const int grid = (int)gridDim.x;
    const int nt = (tiles - bid + grid - 1) / grid;   // tiles for this block

    const float MIND = (float)(0.01 * M_PI / 33.0);   // RATE*pi/(ORDER+1)
    const float PI_F = (float)M_PI;
    const float HI = PI_F - MIND;

    float4* s4 = (float4*)smem;
    float4 r[9];                  // 36 VGPRs of staging, statically indexed

    // Prologue: issue tile 0's loads; consumed by first staging ds_write.
    {
        const float4* g4 = (const float4*)(in + (size_t)bid * FPT);
#pragma unroll
        for (int j = 0; j < 8; ++j) r[j] = g4[tid + j * THREADS];
        if (tid < TAIL) r[8] = g4[tid + 8 * THREADS];
    }

    for (int t = 0; t < nt; ++t) {
        const size_t tile = (size_t)bid + (size_t)t * grid;

        // Stage tile t: regs -> LDS (compiler inserts counted vmcnt per r[j]).
#pragma unroll
        for (int j = 0; j < 8; ++j) s4[tid + j * THREADS] = r[j];
        if (tid < TAIL) s4[tid + 8 * THREADS] = r[8];

        // Issue tile t+1's loads now; they drain under the compute below
        // and are next consumed at the TOP of the next iteration.
        if (t + 1 < nt) {
            const float4* g4 = (const float4*)(in + (tile + grid) * FPT);
#pragma unroll
            for (int j = 0; j < 8; ++j) r[j] = g4[tid + j * THREADS];
            if (tid < TAIL) r[8] = g4[tid + 8 * THREADS];
        }

        // Each thread owns one row; w1 (32 elems) in registers. Same-wave
        // ds_write -> ds_read needs no barrier (in-order per-wave DS pipe;
        // compiler orders via lgkmcnt). LDS row stride 33 -> 2-way bank
        // aliasing across wave64 (free, m136).
        float w[32];
        float* row = smem + tid * ROW;
#pragma unroll
        for (int k = 0; k < 32; ++k) w[k] = row[k + 1];

#pragma unroll
        for (int it = 0; it < 4; ++it) {
            float c = w[0];
#pragma unroll
            for (int k = 1; k < 32; ++k) {
                float nxt = w[k];
                float sft = 0.5f * fmaxf(MIND - (nxt - c), 0.0f);
                w[k - 1] = c - sft;   // 0.5*m exact (pow2 mul) -> fma-safe
                c = nxt + sft;
            }
            w[31] = c;
#pragma unroll
            for (int k = 0; k < 32; ++k)
                w[k] = fminf(fmaxf(w[k], MIND), HI);
        }

        // K (element 0) untouched in LDS; write back w1 only.
#pragma unroll
        for (int k = 0; k < 32; ++k) row[k + 1] = w[k];

        // Coalesced LDS -> global store (9 x ds_read_b128 + store_dwordx4).
        // Next iteration's staging writes are ordered after these ds_reads
        // by the in-order DS pipe -> single buffer is WAR-safe.
        float4* out4 = (float4*)(out + tile * FPT);
#pragma unroll
        for (int j = 0; j < 8; ++j)
            out4[tid + j * THREADS] = s4[tid + j * THREADS];
        if (tid < TAIL)
            out4[tid + 8 * THREADS] = s4[tid + 8 * THREADS];
    }
}

extern "C" void kernel_launch(void* const* d_in, const int* in_sizes, int n_in,
                              void* d_out, int out_size, void* d_ws, size_t ws_size,
                              hipStream_t stream) {
    const float* in = (const float*)d_in[0];
    float* out = (float*)d_out;
    // total = 256*4096*33 = 34,603,008 floats; 2112 per tile -> 16384 tiles.
    const int tiles = in_sizes[0] / FPT;
    const int blocks = tiles < GRID ? tiles : GRID;   // 4096 -> 4 tiles/block
    lsp_stability_kernel<<<blocks, THREADS, 0, stream>>>(in, out, tiles);
}

// Round 3
// 228.965 us; speedup vs baseline: 1.1525x; 1.1525x over previous
//
#include <hip/hip_runtime.h>
#include <math.h>

// (256, 4096, 33) f32 rows: [K, w1[0..31]]; K passes through; w1 gets
// 4x (31-step push-apart scan + clip). One thread per row, row in registers.
//
// R4 post-mortem: reg-staged pipeline DID unlock the pipe (2.5 -> 3.9 TB/s,
// so global_load_lds ingest was indeed rate-capped), but HBM traffic
// DOUBLED: WRITE 135 -> 276 MB (= 2x output), FETCH 67 -> 130 MB. Regular
// vector loads ALLOCATE in L2/LLC; this kernel is a one-touch stream, so
// the allocations churn dirty lines (harness poison fill + our own output)
// out to HBM and evict the input residency that R1-R3 enjoyed. DMA loads
// don't allocate that way (low traffic) but cap at ~2.5 TB/s.
// R5: same pipeline, but NON-TEMPORAL loads AND stores
// (__builtin_nontemporal_load/store -> 'nt' flag on global_load/store):
// no allocation on the streaming read, no retention of the written lines.
// The harness's own fills (streaming stores, 6.6 TB/s, FETCH~0) prove nt
// stores run at full rate with no fetch inflation.
// Predicted: WRITE ~138 MB, FETCH ~138 MB, BW >= 5.5 TB/s, ~45-50 us.

#define THREADS 64
#define ROW 33
#define TROWS 64                  // rows per tile (= one wave)
#define FPT (TROWS * ROW)         // 2112 floats per tile (8448 B)
#define V4PT (FPT / 4)            // 528 float4 per tile
#define TAIL (V4PT - 8 * THREADS) // 16-lane ragged tail
#define GRID 4096                 // 16 blocks/CU, 4 tiles per block

typedef __attribute__((ext_vector_type(4))) float v4f;

__global__ __launch_bounds__(THREADS) void lsp_stability_kernel(
    const float* __restrict__ in, float* __restrict__ out, int tiles)
{
    __shared__ alignas(16) float smem[FPT];
    const int tid = threadIdx.x;
    const int bid = blockIdx.x;
    if (bid >= tiles) return;
    const int grid = (int)gridDim.x;
    const int nt = (tiles - bid + grid - 1) / grid;   // tiles for this block

    const float MIND = (float)(0.01 * M_PI / 33.0);   // RATE*pi/(ORDER+1)
    const float PI_F = (float)M_PI;
    const float HI = PI_F - MIND;

    v4f* s4 = (v4f*)smem;
    v4f r[9];                     // 36 VGPRs of staging, statically indexed

    // Prologue: issue tile 0's loads; consumed by first staging ds_write.
    {
        const v4f* g4 = (const v4f*)(in + (size_t)bid * FPT);
#pragma unroll
        for (int j = 0; j < 8; ++j)
            r[j] = __builtin_nontemporal_load(g4 + tid + j * THREADS);
        if (tid < TAIL)
            r[8] = __builtin_nontemporal_load(g4 + tid + 8 * THREADS);
    }

    for (int t = 0; t < nt; ++t) {
        const size_t tile = (size_t)bid + (size_t)t * grid;

        // Stage tile t: regs -> LDS (compiler inserts counted vmcnt per r[j]).
#pragma unroll
        for (int j = 0; j < 8; ++j) s4[tid + j * THREADS] = r[j];
        if (tid < TAIL) s4[tid + 8 * THREADS] = r[8];

        // Issue tile t+1's loads now; they drain under the compute below
        // and are next consumed at the TOP of the next iteration.
        if (t + 1 < nt) {
            const v4f* g4 = (const v4f*)(in + (tile + grid) * FPT);
#pragma unroll
            for (int j = 0; j < 8; ++j)
                r[j] = __builtin_nontemporal_load(g4 + tid + j * THREADS);
            if (tid < TAIL)
                r[8] = __builtin_nontemporal_load(g4 + tid + 8 * THREADS);
        }

        // Each thread owns one row; w1 (32 elems) in registers. Same-wave
        // ds_write -> ds_read needs no barrier (in-order per-wave DS pipe;
        // compiler orders via lgkmcnt). LDS row stride 33 -> 2-way bank
        // aliasing across wave64 (free, m136).
        float w[32];
        float* row = smem + tid * ROW;
#pragma unroll
        for (int k = 0; k < 32; ++k) w[k] = row[k + 1];

#pragma unroll
        for (int it = 0; it < 4; ++it) {
            float c = w[0];
#pragma unroll
            for (int k = 1; k < 32; ++k) {
                float nxt = w[k];
                float sft = 0.5f * fmaxf(MIND - (nxt - c), 0.0f);
                w[k - 1] = c - sft;   // 0.5*m exact (pow2 mul) -> fma-safe
                c = nxt + sft;
            }
            w[31] = c;
#pragma unroll
            for (int k = 0; k < 32; ++k)
                w[k] = fminf(fmaxf(w[k], MIND), HI);
        }

        // K (element 0) untouched in LDS; write back w1 only.
#pragma unroll
        for (int k = 0; k < 32; ++k) row[k + 1] = w[k];

        // Coalesced LDS -> global nt store (ds_read_b128 + store_dwordx4 nt).
        // Next iteration's staging ds_writes are ordered after these
        // ds_reads by the in-order DS pipe -> single buffer is WAR-safe.
        v4f* out4 = (v4f*)(out + tile * FPT);
#pragma unroll
        for (int j = 0; j < 8; ++j)
            __builtin_nontemporal_store(s4[tid + j * THREADS],
                                        out4 + tid + j * THREADS);
        if (tid < TAIL)
            __builtin_nontemporal_store(s4[tid + 8 * THREADS],
                                        out4 + tid + 8 * THREADS);
    }
}

extern "C" void kernel_launch(void* const* d_in, const int* in_sizes, int n_in,
                              void* d_out, int out_size, void* d_ws, size_t ws_size,
                              hipStream_t stream) {
    const float* in = (const float*)d_in[0];
    float* out = (float*)d_out;
    // total = 256*4096*33 = 34,603,008 floats; 2112 per tile -> 16384 tiles.
    const int tiles = in_sizes[0] / FPT;
    const int blocks = tiles < GRID ? tiles : GRID;   // 4096 -> 4 tiles/block
    lsp_stability_kernel<<<blocks, THREADS, 0, stream>>>(in, out, tiles);
}